// Round 1
// baseline (2646.313 us; speedup 1.0000x reference)
//
#include <hip/hip_runtime.h>
#include <hip/hip_bf16.h>

// Problem constants
#define B_ 4
#define S1_ 64
#define S2_ 256
#define D_ 256
#define H_ 8
#define HD_ 32
#define F_ 1024
#define EPS_ 1e-5f
#define NEG_ 0.01f

// ---------------------------------------------------------------------------
// Kernel 1: q/k time-conv (K=3, zero-padded) + v projection, fused.
// Grid: (B*S1, S2/16) blocks, 256 threads (thread = output channel).
// LDS holds x transposed [channel][row] so the inner loop reads 18 contiguous
// floats per input channel (broadcast across the wave -> conflict-free).
// ---------------------------------------------------------------------------
__global__ __launch_bounds__(256) void k_qkv(
    const float* __restrict__ x,
    const float* __restrict__ Wq, const float* __restrict__ bq,
    const float* __restrict__ Wk, const float* __restrict__ bk,
    const float* __restrict__ Wv, const float* __restrict__ bv,
    float* __restrict__ q, float* __restrict__ k, float* __restrict__ v)
{
    __shared__ float xT[256][18];   // [in_channel][row t0-1 .. t0+16]
    const int bn   = blockIdx.x;    // 0..255  (b*S1+n)
    const int t0   = blockIdx.y * 16;
    const int c    = threadIdx.x;   // output channel 0..255
    const float* xbase = x + (size_t)bn * S2_ * D_;

    #pragma unroll
    for (int r = 0; r < 18; ++r) {
        int t = t0 - 1 + r;
        xT[c][r] = (t >= 0 && t < S2_) ? xbase[(size_t)t * D_ + c] : 0.f;
    }
    __syncthreads();

    float accq[16], acck[16], accv[16];
    #pragma unroll
    for (int t = 0; t < 16; ++t) { accq[t] = 0.f; acck[t] = 0.f; accv[t] = 0.f; }

    for (int i = 0; i < 256; ++i) {
        float xv[18];
        #pragma unroll
        for (int r = 0; r < 18; ++r) xv[r] = xT[i][r];
        const float wq0 = Wq[(0 * D_ + i) * D_ + c];
        const float wq1 = Wq[(1 * D_ + i) * D_ + c];
        const float wq2 = Wq[(2 * D_ + i) * D_ + c];
        const float wk0 = Wk[(0 * D_ + i) * D_ + c];
        const float wk1 = Wk[(1 * D_ + i) * D_ + c];
        const float wk2 = Wk[(2 * D_ + i) * D_ + c];
        const float wvv = Wv[i * D_ + c];
        #pragma unroll
        for (int t = 0; t < 16; ++t) {
            accq[t] = fmaf(xv[t],     wq0, accq[t]);
            accq[t] = fmaf(xv[t + 1], wq1, accq[t]);
            accq[t] = fmaf(xv[t + 2], wq2, accq[t]);
            acck[t] = fmaf(xv[t],     wk0, acck[t]);
            acck[t] = fmaf(xv[t + 1], wk1, acck[t]);
            acck[t] = fmaf(xv[t + 2], wk2, acck[t]);
            accv[t] = fmaf(xv[t + 1], wvv, accv[t]);
        }
    }

    const float bqc = bq[c], bkc = bk[c], bvc = bv[c];
    #pragma unroll
    for (int t = 0; t < 16; ++t) {
        size_t idx = ((size_t)bn * S2_ + (t0 + t)) * D_ + c;
        q[idx] = accq[t] + bqc;
        k[idx] = acck[t] + bkc;
        v[idx] = accv[t] + bvc;
    }
}

// ---------------------------------------------------------------------------
// Kernel 2: attention over time per (b*n, head). One thread per query row,
// K/V head slice (2 x 32 KB) staged in LDS, online softmax in registers.
// ---------------------------------------------------------------------------
__global__ __launch_bounds__(256) void k_attn(
    const float* __restrict__ q, const float* __restrict__ k,
    const float* __restrict__ v, float* __restrict__ o)
{
    __shared__ float Kl[256][32];
    __shared__ float Vl[256][32];
    const int bn  = blockIdx.x;   // 0..255
    const int h   = blockIdx.y;   // 0..7
    const int tid = threadIdx.x;
    const size_t base = (size_t)bn * S2_ * D_ + h * HD_;

    {
        const int j4   = (tid & 7) * 4;  // float4 column
        const int trow = tid >> 3;       // 0..31
        for (int it = 0; it < 8; ++it) {
            int t = it * 32 + trow;
            float4 kk4 = *(const float4*)(k + base + (size_t)t * D_ + j4);
            float4 vv4 = *(const float4*)(v + base + (size_t)t * D_ + j4);
            *(float4*)&Kl[t][j4] = kk4;
            *(float4*)&Vl[t][j4] = vv4;
        }
    }
    __syncthreads();

    const int t = tid;
    float qv[32];
    #pragma unroll
    for (int j = 0; j < 32; ++j)
        qv[j] = q[base + (size_t)t * D_ + j] * 0.17677669529663687f; // 1/sqrt(32)

    float m = -1e30f, l = 0.f;
    float acc[32];
    #pragma unroll
    for (int j = 0; j < 32; ++j) acc[j] = 0.f;

    for (int s = 0; s < 256; ++s) {
        float sc = 0.f;
        #pragma unroll
        for (int j = 0; j < 32; ++j) sc = fmaf(qv[j], Kl[s][j], sc);
        if (sc > m) {
            const float scale = __expf(m - sc);
            l *= scale;
            #pragma unroll
            for (int j = 0; j < 32; ++j) acc[j] *= scale;
            m = sc;
        }
        const float e = __expf(sc - m);
        l += e;
        #pragma unroll
        for (int j = 0; j < 32; ++j) acc[j] = fmaf(e, Vl[s][j], acc[j]);
    }

    const float inv = 1.f / l;
    #pragma unroll
    for (int j = 0; j < 32; ++j)
        o[base + (size_t)t * D_ + j] = acc[j] * inv;
}

// ---------------------------------------------------------------------------
// Kernel 3: o @ Wo + bo + residual(x) -> LayerNorm(g1,be1) -> h
// Grid: 4096 blocks of 16 tokens; thread = channel.
// ---------------------------------------------------------------------------
__global__ __launch_bounds__(256) void k_oproj_ln1(
    const float* __restrict__ x, const float* __restrict__ o,
    const float* __restrict__ Wo, const float* __restrict__ bo,
    const float* __restrict__ g1, const float* __restrict__ be1,
    float* __restrict__ hout)
{
    __shared__ float oT[256][17];    // [channel][local_token]
    __shared__ float mu_s[16], rs_s[16];
    const int d = threadIdx.x;
    const size_t tok0 = (size_t)blockIdx.x * 16;

    #pragma unroll
    for (int lt = 0; lt < 16; ++lt)
        oT[d][lt] = o[(tok0 + lt) * D_ + d];
    __syncthreads();

    float acc[16];
    #pragma unroll
    for (int lt = 0; lt < 16; ++lt) acc[lt] = 0.f;

    for (int kk = 0; kk < 256; ++kk) {
        const float w = Wo[kk * D_ + d];
        #pragma unroll
        for (int lt = 0; lt < 16; ++lt)
            acc[lt] = fmaf(oT[kk][lt], w, acc[lt]);
    }

    const float bod = bo[d];
    float yv[16];
    #pragma unroll
    for (int lt = 0; lt < 16; ++lt)
        yv[lt] = acc[lt] + bod + x[(tok0 + lt) * D_ + d];

    __syncthreads();                 // done reading oT
    #pragma unroll
    for (int lt = 0; lt < 16; ++lt) oT[d][lt] = yv[lt];  // reuse as yT
    __syncthreads();

    if (d < 16) {
        float s = 0.f, s2 = 0.f;
        for (int c = 0; c < 256; ++c) {
            const float val = oT[c][d];
            s += val; s2 = fmaf(val, val, s2);
        }
        const float mu  = s * (1.f / 256.f);
        const float var = s2 * (1.f / 256.f) - mu * mu;
        mu_s[d] = mu;
        rs_s[d] = rsqrtf(var + EPS_);
    }
    __syncthreads();

    const float g = g1[d], be = be1[d];
    #pragma unroll
    for (int lt = 0; lt < 16; ++lt)
        hout[(tok0 + lt) * D_ + d] = (yv[lt] - mu_s[lt]) * rs_s[lt] * g + be;
}

// ---------------------------------------------------------------------------
// Kernel 4: fused FFN (leaky ReLU) + residual + LayerNorm(g2,be2) -> out.
// ff1 tile lives in LDS (F split into two 512-halves); never materialized
// in global memory. Grid: 4096 blocks of 16 tokens; thread = channel.
// ---------------------------------------------------------------------------
__global__ __launch_bounds__(256) void k_ffn_ln2(
    const float* __restrict__ h,
    const float* __restrict__ W1, const float* __restrict__ b1,
    const float* __restrict__ W2, const float* __restrict__ b2,
    const float* __restrict__ g2, const float* __restrict__ be2,
    float* __restrict__ out)
{
    __shared__ float hT[256][17];    // [channel][local_token]
    __shared__ float ffT[512][17];   // [f_local][local_token]
    __shared__ float mu_s[16], rs_s[16];
    const int tid = threadIdx.x;
    const size_t tok0 = (size_t)blockIdx.x * 16;

    #pragma unroll
    for (int lt = 0; lt < 16; ++lt)
        hT[tid][lt] = h[(tok0 + lt) * D_ + tid];
    __syncthreads();

    float acc2[16];
    #pragma unroll
    for (int lt = 0; lt < 16; ++lt) acc2[lt] = 0.f;

    for (int hf = 0; hf < 2; ++hf) {
        const int f0 = hf * 512 + tid * 2;
        float a0[16], a1[16];
        #pragma unroll
        for (int lt = 0; lt < 16; ++lt) { a0[lt] = 0.f; a1[lt] = 0.f; }

        for (int kk = 0; kk < 256; ++kk) {
            const float2 w = *(const float2*)(W1 + (size_t)kk * F_ + f0);
            #pragma unroll
            for (int lt = 0; lt < 16; ++lt) {
                const float hv = hT[kk][lt];
                a0[lt] = fmaf(hv, w.x, a0[lt]);
                a1[lt] = fmaf(hv, w.y, a1[lt]);
            }
        }

        const float b10 = b1[f0], b11 = b1[f0 + 1];
        __syncthreads();   // previous half's phase-2 done reading ffT
        #pragma unroll
        for (int lt = 0; lt < 16; ++lt) {
            float p0 = a0[lt] + b10;
            float p1 = a1[lt] + b11;
            p0 = (p0 > 0.f) ? p0 : NEG_ * p0;
            p1 = (p1 > 0.f) ? p1 : NEG_ * p1;
            ffT[tid * 2][lt]     = p0;
            ffT[tid * 2 + 1][lt] = p1;
        }
        __syncthreads();

        const float* W2h = W2 + (size_t)hf * 512 * D_;
        for (int fp = 0; fp < 512; ++fp) {
            const float w = W2h[(size_t)fp * D_ + tid];
            #pragma unroll
            for (int lt = 0; lt < 16; ++lt)
                acc2[lt] = fmaf(ffT[fp][lt], w, acc2[lt]);
        }
    }

    const float b2d = b2[tid];
    float yv[16];
    #pragma unroll
    for (int lt = 0; lt < 16; ++lt)
        yv[lt] = acc2[lt] + b2d + hT[tid][lt];

    __syncthreads();                 // done reading ffT
    #pragma unroll
    for (int lt = 0; lt < 16; ++lt) ffT[tid][lt] = yv[lt];  // reuse as yT
    __syncthreads();

    if (tid < 16) {
        float s = 0.f, s2 = 0.f;
        for (int c = 0; c < 256; ++c) {
            const float val = ffT[c][tid];
            s += val; s2 = fmaf(val, val, s2);
        }
        const float mu  = s * (1.f / 256.f);
        const float var = s2 * (1.f / 256.f) - mu * mu;
        mu_s[tid] = mu;
        rs_s[tid] = rsqrtf(var + EPS_);
    }
    __syncthreads();

    const float g = g2[tid], be = be2[tid];
    #pragma unroll
    for (int lt = 0; lt < 16; ++lt)
        out[(tok0 + lt) * D_ + tid] = (yv[lt] - mu_s[lt]) * rs_s[lt] * g + be;
}

// ---------------------------------------------------------------------------
extern "C" void kernel_launch(void* const* d_in, const int* in_sizes, int n_in,
                              void* d_out, int out_size, void* d_ws, size_t ws_size,
                              hipStream_t stream)
{
    const float* x   = (const float*)d_in[0];
    const float* Wq  = (const float*)d_in[1];
    const float* bq  = (const float*)d_in[2];
    const float* Wk  = (const float*)d_in[3];
    const float* bk  = (const float*)d_in[4];
    const float* Wv  = (const float*)d_in[5];
    const float* bv  = (const float*)d_in[6];
    const float* Wo  = (const float*)d_in[7];
    const float* bo  = (const float*)d_in[8];
    const float* W1  = (const float*)d_in[9];
    const float* b1  = (const float*)d_in[10];
    const float* W2  = (const float*)d_in[11];
    const float* b2  = (const float*)d_in[12];
    const float* g1  = (const float*)d_in[13];
    const float* be1 = (const float*)d_in[14];
    const float* g2  = (const float*)d_in[15];
    const float* be2 = (const float*)d_in[16];
    float* out = (float*)d_out;

    const size_t N = (size_t)B_ * S1_ * S2_ * D_;   // 16,777,216 elements
    if (ws_size < 4 * N * sizeof(float)) return;    // need 256 MB scratch

    float* q = (float*)d_ws;
    float* k = q + N;
    float* v = k + N;
    float* o = v + N;
    float* h = q;   // q is dead after attention; reuse its buffer for h

    k_qkv     <<<dim3(B_ * S1_, S2_ / 16), 256, 0, stream>>>(x, Wq, bq, Wk, bk, Wv, bv, q, k, v);
    k_attn    <<<dim3(B_ * S1_, H_),       256, 0, stream>>>(q, k, v, o);
    k_oproj_ln1<<<dim3(B_ * S1_ * S2_ / 16), 256, 0, stream>>>(x, o, Wo, bo, g1, be1, h);
    k_ffn_ln2 <<<dim3(B_ * S1_ * S2_ / 16), 256, 0, stream>>>(h, W1, b1, W2, b2, g2, be2, out);
}

// Round 2
// 1795.166 us; speedup vs baseline: 1.4741x; 1.4741x over previous
//
#include <hip/hip_runtime.h>
#include <hip/hip_bf16.h>

// Problem constants
#define B_ 4
#define S1_ 64
#define S2_ 256
#define D_ 256
#define H_ 8
#define HD_ 32
#define F_ 1024
#define EPS_ 1e-5f
#define NEG_ 0.01f

typedef __attribute__((ext_vector_type(8))) short bfrag;   // 8 x bf16 (4 VGPRs)
typedef __attribute__((ext_vector_type(4))) float f32x4;   // MFMA C/D

__device__ __forceinline__ unsigned short bf16rn(float f) {
    union { float f; unsigned int u; } c; c.f = f;
    unsigned int u = c.u;
    u = (u + 0x7FFFu + ((u >> 16) & 1u)) >> 16;   // round-to-nearest-even
    return (unsigned short)u;
}

// ---------------------------------------------------------------------------
// Kernel 1: q/k time-conv (K=3, zero-padded) + v projection, fused. (fp32)
// ---------------------------------------------------------------------------
__global__ __launch_bounds__(256) void k_qkv(
    const float* __restrict__ x,
    const float* __restrict__ Wq, const float* __restrict__ bq,
    const float* __restrict__ Wk, const float* __restrict__ bk,
    const float* __restrict__ Wv, const float* __restrict__ bv,
    float* __restrict__ q, float* __restrict__ k, float* __restrict__ v)
{
    __shared__ float xT[256][18];   // [in_channel][row t0-1 .. t0+16]
    const int bn   = blockIdx.x;    // 0..255  (b*S1+n)
    const int t0   = blockIdx.y * 16;
    const int c    = threadIdx.x;   // output channel 0..255
    const float* xbase = x + (size_t)bn * S2_ * D_;

    #pragma unroll
    for (int r = 0; r < 18; ++r) {
        int t = t0 - 1 + r;
        xT[c][r] = (t >= 0 && t < S2_) ? xbase[(size_t)t * D_ + c] : 0.f;
    }
    __syncthreads();

    float accq[16], acck[16], accv[16];
    #pragma unroll
    for (int t = 0; t < 16; ++t) { accq[t] = 0.f; acck[t] = 0.f; accv[t] = 0.f; }

    for (int i = 0; i < 256; ++i) {
        float xv[18];
        #pragma unroll
        for (int r = 0; r < 18; ++r) xv[r] = xT[i][r];
        const float wq0 = Wq[(0 * D_ + i) * D_ + c];
        const float wq1 = Wq[(1 * D_ + i) * D_ + c];
        const float wq2 = Wq[(2 * D_ + i) * D_ + c];
        const float wk0 = Wk[(0 * D_ + i) * D_ + c];
        const float wk1 = Wk[(1 * D_ + i) * D_ + c];
        const float wk2 = Wk[(2 * D_ + i) * D_ + c];
        const float wvv = Wv[i * D_ + c];
        #pragma unroll
        for (int t = 0; t < 16; ++t) {
            accq[t] = fmaf(xv[t],     wq0, accq[t]);
            accq[t] = fmaf(xv[t + 1], wq1, accq[t]);
            accq[t] = fmaf(xv[t + 2], wq2, accq[t]);
            acck[t] = fmaf(xv[t],     wk0, acck[t]);
            acck[t] = fmaf(xv[t + 1], wk1, acck[t]);
            acck[t] = fmaf(xv[t + 2], wk2, acck[t]);
            accv[t] = fmaf(xv[t + 1], wvv, accv[t]);
        }
    }

    const float bqc = bq[c], bkc = bk[c], bvc = bv[c];
    #pragma unroll
    for (int t = 0; t < 16; ++t) {
        size_t idx = ((size_t)bn * S2_ + (t0 + t)) * D_ + c;
        q[idx] = accq[t] + bqc;
        k[idx] = acck[t] + bkc;
        v[idx] = accv[t] + bvc;
    }
}

// ---------------------------------------------------------------------------
// Kernel 2: attention over time per (b*n, head). (fp32, unchanged)
// ---------------------------------------------------------------------------
__global__ __launch_bounds__(256) void k_attn(
    const float* __restrict__ q, const float* __restrict__ k,
    const float* __restrict__ v, float* __restrict__ o)
{
    __shared__ float Kl[256][32];
    __shared__ float Vl[256][32];
    const int bn  = blockIdx.x;   // 0..255
    const int h   = blockIdx.y;   // 0..7
    const int tid = threadIdx.x;
    const size_t base = (size_t)bn * S2_ * D_ + h * HD_;

    {
        const int j4   = (tid & 7) * 4;  // float4 column
        const int trow = tid >> 3;       // 0..31
        for (int it = 0; it < 8; ++it) {
            int t = it * 32 + trow;
            float4 kk4 = *(const float4*)(k + base + (size_t)t * D_ + j4);
            float4 vv4 = *(const float4*)(v + base + (size_t)t * D_ + j4);
            *(float4*)&Kl[t][j4] = kk4;
            *(float4*)&Vl[t][j4] = vv4;
        }
    }
    __syncthreads();

    const int t = tid;
    float qv[32];
    #pragma unroll
    for (int j = 0; j < 32; ++j)
        qv[j] = q[base + (size_t)t * D_ + j] * 0.17677669529663687f; // 1/sqrt(32)

    float m = -1e30f, l = 0.f;
    float acc[32];
    #pragma unroll
    for (int j = 0; j < 32; ++j) acc[j] = 0.f;

    for (int s = 0; s < 256; ++s) {
        float sc = 0.f;
        #pragma unroll
        for (int j = 0; j < 32; ++j) sc = fmaf(qv[j], Kl[s][j], sc);
        if (sc > m) {
            const float scale = __expf(m - sc);
            l *= scale;
            #pragma unroll
            for (int j = 0; j < 32; ++j) acc[j] *= scale;
            m = sc;
        }
        const float e = __expf(sc - m);
        l += e;
        #pragma unroll
        for (int j = 0; j < 32; ++j) acc[j] = fmaf(e, Vl[s][j], acc[j]);
    }

    const float inv = 1.f / l;
    #pragma unroll
    for (int j = 0; j < 32; ++j)
        o[base + (size_t)t * D_ + j] = acc[j] * inv;
}

// ---------------------------------------------------------------------------
// Kernel 3: o @ Wo + bo + residual(x) -> LayerNorm(g1,be1) -> h (fp32)
// ---------------------------------------------------------------------------
__global__ __launch_bounds__(256) void k_oproj_ln1(
    const float* __restrict__ x, const float* __restrict__ o,
    const float* __restrict__ Wo, const float* __restrict__ bo,
    const float* __restrict__ g1, const float* __restrict__ be1,
    float* __restrict__ hout)
{
    __shared__ float oT[256][17];    // [channel][local_token]
    __shared__ float mu_s[16], rs_s[16];
    const int d = threadIdx.x;
    const size_t tok0 = (size_t)blockIdx.x * 16;

    #pragma unroll
    for (int lt = 0; lt < 16; ++lt)
        oT[d][lt] = o[(tok0 + lt) * D_ + d];
    __syncthreads();

    float acc[16];
    #pragma unroll
    for (int lt = 0; lt < 16; ++lt) acc[lt] = 0.f;

    for (int kk = 0; kk < 256; ++kk) {
        const float w = Wo[kk * D_ + d];
        #pragma unroll
        for (int lt = 0; lt < 16; ++lt)
            acc[lt] = fmaf(oT[kk][lt], w, acc[lt]);
    }

    const float bod = bo[d];
    float yv[16];
    #pragma unroll
    for (int lt = 0; lt < 16; ++lt)
        yv[lt] = acc[lt] + bod + x[(tok0 + lt) * D_ + d];

    __syncthreads();                 // done reading oT
    #pragma unroll
    for (int lt = 0; lt < 16; ++lt) oT[d][lt] = yv[lt];  // reuse as yT
    __syncthreads();

    if (d < 16) {
        float s = 0.f, s2 = 0.f;
        for (int c = 0; c < 256; ++c) {
            const float val = oT[c][d];
            s += val; s2 = fmaf(val, val, s2);
        }
        const float mu  = s * (1.f / 256.f);
        const float var = s2 * (1.f / 256.f) - mu * mu;
        mu_s[d] = mu;
        rs_s[d] = rsqrtf(var + EPS_);
    }
    __syncthreads();

    const float g = g1[d], be = be1[d];
    #pragma unroll
    for (int lt = 0; lt < 16; ++lt)
        hout[(tok0 + lt) * D_ + d] = (yv[lt] - mu_s[lt]) * rs_s[lt] * g + be;
}

// ---------------------------------------------------------------------------
// Weight conversion: W1 fp32 [k=256][n=1024] -> W1bt bf16 [n][k] (B^T layout)
// ---------------------------------------------------------------------------
__global__ __launch_bounds__(256) void k_cvt_w1(
    const float* __restrict__ W1, unsigned short* __restrict__ W1bt)
{
    const int n = blockIdx.x;        // 0..1023
    const int k = threadIdx.x;       // 0..255
    W1bt[(size_t)n * 256 + k] = bf16rn(W1[(size_t)k * F_ + n]);
}

// W2 fp32 [f=1024][d=256] -> W2bt bf16 [d][f]
__global__ __launch_bounds__(256) void k_cvt_w2(
    const float* __restrict__ W2, unsigned short* __restrict__ W2bt)
{
    const int d = blockIdx.x;        // 0..255
    for (int f = threadIdx.x; f < F_; f += 256)
        W2bt[(size_t)d * F_ + f] = bf16rn(W2[(size_t)f * D_ + d]);
}

// ---------------------------------------------------------------------------
// Kernel 4: FFN via bf16 MFMA, fused leakyReLU + residual + LN2.
// Block = 256 thr = 4 waves, M = 32 tokens. F split into 2 halves of 512 so
// the ff tile stays in LDS (never hits global). Layouts (HW-verified):
//   A-frag: A[m = lane&15][k = quad*8 + j]
//   B-frag: B^T row-major, B[n = lane&15][k = quad*8 + j]
//   C/D   : col(n) = lane&15, row(m) = quad*4 + reg
// ---------------------------------------------------------------------------
__global__ __launch_bounds__(256) void k_ffn_mfma(
    const float* __restrict__ h,
    const unsigned short* __restrict__ W1bt, const float* __restrict__ b1,
    const unsigned short* __restrict__ W2bt, const float* __restrict__ b2,
    const float* __restrict__ g2, const float* __restrict__ be2,
    float* __restrict__ out)
{
    __shared__ __align__(16) unsigned short hA[32][264];   // h tokens, bf16, A-layout
    __shared__ __align__(16) unsigned short ffA[32][520];  // ff half-tile / epilogue y (fp32 alias)
    __shared__ float red[32][8][2];
    __shared__ float mu_s[32], rs_s[32];

    const int tid  = threadIdx.x;
    const int w    = tid >> 6;      // wave 0..3
    const int lane = tid & 63;
    const int col  = lane & 15;
    const int q4   = lane >> 4;     // quad 0..3
    const size_t tok0 = (size_t)blockIdx.x * 32;

    // stage h -> bf16 LDS (coalesced fp32 reads)
    for (int i = 0; i < 32; ++i)
        hA[i][tid] = bf16rn(h[(tok0 + i) * D_ + tid]);
    __syncthreads();

    // preload all A fragments for GEMM1 (K=256 -> 8 chunks, 2 M-tiles)
    bfrag a[2][8];
    #pragma unroll
    for (int mt = 0; mt < 2; ++mt)
        #pragma unroll
        for (int kc = 0; kc < 8; ++kc)
            a[mt][kc] = *(const bfrag*)&hA[mt * 16 + col][kc * 32 + q4 * 8];

    f32x4 acc2[2][4];
    #pragma unroll
    for (int mt = 0; mt < 2; ++mt)
        #pragma unroll
        for (int t2 = 0; t2 < 4; ++t2)
            acc2[mt][t2] = (f32x4){0.f, 0.f, 0.f, 0.f};

    for (int hf = 0; hf < 2; ++hf) {
        // ---- GEMM1 half: ff[:, hf*512 .. +512) ; wave w owns 128 n-cols ----
        for (int t = 0; t < 8; ++t) {
            const int ng = hf * 512 + w * 128 + t * 16;     // global n of this tile
            const unsigned short* bp = W1bt + (size_t)(ng + col) * 256 + q4 * 8;
            f32x4 c0 = {0.f, 0.f, 0.f, 0.f}, c1 = {0.f, 0.f, 0.f, 0.f};
            #pragma unroll
            for (int kc = 0; kc < 8; ++kc) {
                bfrag b = *(const bfrag*)(bp + kc * 32);
                c0 = __builtin_amdgcn_mfma_f32_16x16x32_bf16(a[0][kc], b, c0, 0, 0, 0);
                c1 = __builtin_amdgcn_mfma_f32_16x16x32_bf16(a[1][kc], b, c1, 0, 0, 0);
            }
            const float bb   = b1[ng + col];
            const int   nloc = w * 128 + t * 16 + col;      // col within half
            #pragma unroll
            for (int r = 0; r < 4; ++r) {
                float v0 = c0[r] + bb; v0 = (v0 > 0.f) ? v0 : NEG_ * v0;
                float v1 = c1[r] + bb; v1 = (v1 > 0.f) ? v1 : NEG_ * v1;
                ffA[q4 * 4 + r][nloc]      = bf16rn(v0);
                ffA[16 + q4 * 4 + r][nloc] = bf16rn(v1);
            }
        }
        __syncthreads();

        // ---- GEMM2 partial: y += ff_half @ W2[hf*512 .. +512, :] ----
        for (int kc = 0; kc < 16; ++kc) {
            bfrag a0 = *(const bfrag*)&ffA[col][kc * 32 + q4 * 8];
            bfrag a1 = *(const bfrag*)&ffA[16 + col][kc * 32 + q4 * 8];
            #pragma unroll
            for (int t2 = 0; t2 < 4; ++t2) {
                const int d0 = w * 64 + t2 * 16;
                bfrag b = *(const bfrag*)(W2bt + (size_t)(d0 + col) * F_
                                          + hf * 512 + kc * 32 + q4 * 8);
                acc2[0][t2] = __builtin_amdgcn_mfma_f32_16x16x32_bf16(a0, b, acc2[0][t2], 0, 0, 0);
                acc2[1][t2] = __builtin_amdgcn_mfma_f32_16x16x32_bf16(a1, b, acc2[1][t2], 0, 0, 0);
            }
        }
        __syncthreads();
    }

    // ---- epilogue: y (+b2 +h residual) -> LN -> out ----
    // reuse ffA's storage as fp32 [32][260] (row stride 1040 B matches exactly;
    // barriers above order the type-punned accesses)
    float* yS = (float*)&ffA[0][0];
    #pragma unroll
    for (int mt = 0; mt < 2; ++mt)
        #pragma unroll
        for (int t2 = 0; t2 < 4; ++t2)
            #pragma unroll
            for (int r = 0; r < 4; ++r)
                yS[(mt * 16 + q4 * 4 + r) * 260 + (w * 64 + t2 * 16 + col)] = acc2[mt][t2][r];
    __syncthreads();

    const float b2d = b2[tid];
    for (int i = 0; i < 32; ++i) {
        float val = yS[i * 260 + tid] + b2d + h[(tok0 + i) * D_ + tid];
        yS[i * 260 + tid] = val;
    }
    __syncthreads();

    {
        const int tok = tid >> 3, p = tid & 7;
        float s = 0.f, s2 = 0.f;
        for (int d = p * 32; d < p * 32 + 32; ++d) {
            const float vv = yS[tok * 260 + d];
            s += vv; s2 = fmaf(vv, vv, s2);
        }
        red[tok][p][0] = s; red[tok][p][1] = s2;
    }
    __syncthreads();
    if (tid < 32) {
        float s = 0.f, s2 = 0.f;
        #pragma unroll
        for (int p = 0; p < 8; ++p) { s += red[tid][p][0]; s2 += red[tid][p][1]; }
        const float mu  = s * (1.f / 256.f);
        const float var = s2 * (1.f / 256.f) - mu * mu;
        mu_s[tid] = mu;
        rs_s[tid] = rsqrtf(var + EPS_);
    }
    __syncthreads();

    const float g = g2[tid], be = be2[tid];
    for (int i = 0; i < 32; ++i)
        out[(tok0 + i) * D_ + tid] = (yS[i * 260 + tid] - mu_s[i]) * rs_s[i] * g + be;
}

// ---------------------------------------------------------------------------
extern "C" void kernel_launch(void* const* d_in, const int* in_sizes, int n_in,
                              void* d_out, int out_size, void* d_ws, size_t ws_size,
                              hipStream_t stream)
{
    const float* x   = (const float*)d_in[0];
    const float* Wq  = (const float*)d_in[1];
    const float* bq  = (const float*)d_in[2];
    const float* Wk  = (const float*)d_in[3];
    const float* bk  = (const float*)d_in[4];
    const float* Wv  = (const float*)d_in[5];
    const float* bv  = (const float*)d_in[6];
    const float* Wo  = (const float*)d_in[7];
    const float* bo  = (const float*)d_in[8];
    const float* W1  = (const float*)d_in[9];
    const float* b1  = (const float*)d_in[10];
    const float* W2  = (const float*)d_in[11];
    const float* b2  = (const float*)d_in[12];
    const float* g1  = (const float*)d_in[13];
    const float* be1 = (const float*)d_in[14];
    const float* g2  = (const float*)d_in[15];
    const float* be2 = (const float*)d_in[16];
    float* out = (float*)d_out;

    const size_t N = (size_t)B_ * S1_ * S2_ * D_;   // 16,777,216 elements
    if (ws_size < 4 * N * sizeof(float)) return;    // need 256 MB scratch

    float* q = (float*)d_ws;
    float* k = q + N;
    float* v = k + N;
    float* o = v + N;
    float* h = q;                       // q dead after attention; reuse for h
    // k dead after attention; reuse its 64 MB for bf16 transposed weights
    unsigned short* W1bt = (unsigned short*)k;          // 1024*256 bf16
    unsigned short* W2bt = W1bt + (size_t)F_ * D_;      // 256*1024 bf16

    k_qkv      <<<dim3(B_ * S1_, S2_ / 16), 256, 0, stream>>>(x, Wq, bq, Wk, bk, Wv, bv, q, k, v);
    k_attn     <<<dim3(B_ * S1_, H_),       256, 0, stream>>>(q, k, v, o);
    k_cvt_w1   <<<dim3(F_),  256, 0, stream>>>(W1, W1bt);   // k buffer now dead
    k_cvt_w2   <<<dim3(D_),  256, 0, stream>>>(W2, W2bt);
    k_oproj_ln1<<<dim3(B_ * S1_ * S2_ / 16), 256, 0, stream>>>(x, o, Wo, bo, g1, be1, h);
    k_ffn_mfma <<<dim3(B_ * S1_ * S2_ / 32), 256, 0, stream>>>(h, W1bt, b1, W2bt, b2, g2, be2, out);
}

// Round 4
// 1122.043 us; speedup vs baseline: 2.3585x; 1.5999x over previous
//
#include <hip/hip_runtime.h>
#include <hip/hip_bf16.h>

// Problem constants
#define B_ 4
#define S1_ 64
#define S2_ 256
#define D_ 256
#define H_ 8
#define HD_ 32
#define F_ 1024
#define EPS_ 1e-5f
#define NEG_ 0.01f

typedef __attribute__((ext_vector_type(8))) short bfrag;   // 8 x bf16 (4 VGPRs)
typedef __attribute__((ext_vector_type(4))) float f32x4;   // MFMA C/D

__device__ __forceinline__ unsigned short bf16rn(float f) {
    union { float f; unsigned int u; } c; c.f = f;
    unsigned int u = c.u;
    u = (u + 0x7FFFu + ((u >> 16) & 1u)) >> 16;   // round-to-nearest-even
    return (unsigned short)u;
}
__device__ __forceinline__ float bf2f(unsigned short s) {
    union { unsigned int u; float f; } c; c.u = ((unsigned int)s) << 16;
    return c.f;
}

// ---------------------------------------------------------------------------
// Weight transpose+cast: Wq/Wk [s][i][c] -> Wqk_bt [n=512][k=768] (n<256: q)
//                        Wv [i][c]      -> Wv_bt  [n=256][k=256]
// ---------------------------------------------------------------------------
__global__ __launch_bounds__(256) void k_cvt_qkv(
    const float* __restrict__ Wq, const float* __restrict__ Wk,
    const float* __restrict__ Wv,
    unsigned short* __restrict__ Wqk_bt, unsigned short* __restrict__ Wv_bt)
{
    const int blk = blockIdx.x;      // 0..767
    const int i   = threadIdx.x;     // 0..255 (in-channel)
    if (blk < 256) {
        const int n = blk;
        #pragma unroll
        for (int s = 0; s < 3; ++s)
            Wqk_bt[(size_t)n * 768 + s * 256 + i] = bf16rn(Wq[((size_t)s * 256 + i) * 256 + n]);
    } else if (blk < 512) {
        const int n = blk; const int c = blk - 256;
        #pragma unroll
        for (int s = 0; s < 3; ++s)
            Wqk_bt[(size_t)n * 768 + s * 256 + i] = bf16rn(Wk[((size_t)s * 256 + i) * 256 + c]);
    } else {
        const int c = blk - 512;
        Wv_bt[(size_t)c * 256 + i] = bf16rn(Wv[(size_t)i * 256 + c]);
    }
}

// Wo [k][n] -> Wo_bt [n=256][k=256]; W1 [k][n] -> W1bt [n=1024][k=256];
// W2 [f][d] -> W2bt [d=256][f=1024]
__global__ __launch_bounds__(256) void k_cvt_proj(
    const float* __restrict__ Wo, const float* __restrict__ W1,
    const float* __restrict__ W2,
    unsigned short* __restrict__ Wo_bt, unsigned short* __restrict__ W1bt,
    unsigned short* __restrict__ W2bt)
{
    const int blk = blockIdx.x;      // 0..1535
    const int t   = threadIdx.x;
    if (blk < 256) {
        Wo_bt[(size_t)blk * 256 + t] = bf16rn(Wo[(size_t)t * 256 + blk]);
    } else if (blk < 1280) {
        const int n = blk - 256;     // 0..1023
        W1bt[(size_t)n * 256 + t] = bf16rn(W1[(size_t)t * F_ + n]);
    } else {
        const int d = blk - 1280;    // 0..255
        for (int f = t; f < F_; f += 256)
            W2bt[(size_t)d * F_ + f] = bf16rn(W2[(size_t)f * D_ + d]);
    }
}

// ---------------------------------------------------------------------------
// Kernel 1: q/k time-conv + v projection as bf16 MFMA GEMM.
// Conv-as-GEMM: q[t,c] = sum_s sum_i x[t+s-1,i] * Wq[s,i,c]  (K = 3*256,
// shift-major). Block = 32 tokens of one (b,n); x halo rows t0-1..t0+32
// staged bf16 in LDS; shifted A-fragment = xA[m+s].
// Outputs stored as bf16.
// ---------------------------------------------------------------------------
__global__ __launch_bounds__(256) void k_qkv_mfma(
    const float* __restrict__ x,
    const unsigned short* __restrict__ Wqk_bt,
    const unsigned short* __restrict__ Wv_bt,
    const float* __restrict__ bq, const float* __restrict__ bk,
    const float* __restrict__ bv,
    unsigned short* __restrict__ qb, unsigned short* __restrict__ kb,
    unsigned short* __restrict__ vb)
{
    __shared__ __align__(16) unsigned short xA[34][264];
    const int tid  = threadIdx.x;
    const int w    = tid >> 6;
    const int lane = tid & 63;
    const int col  = lane & 15;
    const int q4   = lane >> 4;
    const int bn   = blockIdx.x >> 3;           // (b*S1+n)
    const int t0   = (blockIdx.x & 7) * 32;
    const float* xb = x + (size_t)bn * S2_ * D_;

    for (int r = 0; r < 34; ++r) {
        const int t = t0 - 1 + r;
        xA[r][tid] = (t >= 0 && t < S2_) ? bf16rn(xb[(size_t)t * D_ + tid])
                                         : (unsigned short)0;
    }
    __syncthreads();

    // ---- q/k: K = 768, shift-major ----
    f32x4 accqk[8][2];
    #pragma unroll
    for (int t = 0; t < 8; ++t)
        #pragma unroll
        for (int mt = 0; mt < 2; ++mt)
            accqk[t][mt] = (f32x4){0.f, 0.f, 0.f, 0.f};

    for (int s = 0; s < 3; ++s) {
        bfrag a[2][8];
        #pragma unroll
        for (int mt = 0; mt < 2; ++mt)
            #pragma unroll
            for (int kc = 0; kc < 8; ++kc)
                a[mt][kc] = *(const bfrag*)&xA[mt * 16 + col + s][kc * 32 + q4 * 8];

        for (int t = 0; t < 8; ++t) {
            const unsigned short* bp =
                Wqk_bt + (size_t)((w * 8 + t) * 16 + col) * 768 + s * 256 + q4 * 8;
            #pragma unroll
            for (int kc = 0; kc < 8; ++kc) {
                bfrag b = *(const bfrag*)(bp + kc * 32);
                accqk[t][0] = __builtin_amdgcn_mfma_f32_16x16x32_bf16(a[0][kc], b, accqk[t][0], 0, 0, 0);
                accqk[t][1] = __builtin_amdgcn_mfma_f32_16x16x32_bf16(a[1][kc], b, accqk[t][1], 0, 0, 0);
            }
        }
    }

    #pragma unroll
    for (int t = 0; t < 8; ++t) {
        const int n = (w * 8 + t) * 16 + col;   // 0..511
        const float bias = (n < 256) ? bq[n] : bk[n - 256];
        unsigned short* dst = (n < 256) ? qb : kb;
        const int c = n & 255;
        #pragma unroll
        for (int mt = 0; mt < 2; ++mt)
            #pragma unroll
            for (int r = 0; r < 4; ++r)
                dst[((size_t)bn * S2_ + t0 + mt * 16 + q4 * 4 + r) * D_ + c]
                    = bf16rn(accqk[t][mt][r] + bias);
    }

    // ---- v: K = 256, center shift ----
    f32x4 accv[4][2];
    #pragma unroll
    for (int t = 0; t < 4; ++t) {
        accv[t][0] = (f32x4){0.f, 0.f, 0.f, 0.f};
        accv[t][1] = (f32x4){0.f, 0.f, 0.f, 0.f};
    }
    bfrag a1[2][8];
    #pragma unroll
    for (int mt = 0; mt < 2; ++mt)
        #pragma unroll
        for (int kc = 0; kc < 8; ++kc)
            a1[mt][kc] = *(const bfrag*)&xA[mt * 16 + col + 1][kc * 32 + q4 * 8];

    for (int t = 0; t < 4; ++t) {
        const unsigned short* bp =
            Wv_bt + (size_t)((w * 4 + t) * 16 + col) * 256 + q4 * 8;
        #pragma unroll
        for (int kc = 0; kc < 8; ++kc) {
            bfrag b = *(const bfrag*)(bp + kc * 32);
            accv[t][0] = __builtin_amdgcn_mfma_f32_16x16x32_bf16(a1[0][kc], b, accv[t][0], 0, 0, 0);
            accv[t][1] = __builtin_amdgcn_mfma_f32_16x16x32_bf16(a1[1][kc], b, accv[t][1], 0, 0, 0);
        }
    }

    #pragma unroll
    for (int t = 0; t < 4; ++t) {
        const int c = (w * 4 + t) * 16 + col;
        const float bias = bv[c];
        #pragma unroll
        for (int mt = 0; mt < 2; ++mt)
            #pragma unroll
            for (int r = 0; r < 4; ++r)
                vb[((size_t)bn * S2_ + t0 + mt * 16 + q4 * 4 + r) * D_ + c]
                    = bf16rn(accv[t][mt][r] + bias);
    }
}

// ---------------------------------------------------------------------------
// Kernel 2: attention over time per (b*n, head). bf16 in, bf16 out,
// fp32 math. One thread per query row; K/V head slice in LDS (fp32).
// ---------------------------------------------------------------------------
__global__ __launch_bounds__(256) void k_attn(
    const unsigned short* __restrict__ qb, const unsigned short* __restrict__ kb,
    const unsigned short* __restrict__ vb, unsigned short* __restrict__ ob)
{
    __shared__ float Kl[256][32];
    __shared__ float Vl[256][32];
    const int bn  = blockIdx.x;   // 0..255
    const int h   = blockIdx.y;   // 0..7
    const int tid = threadIdx.x;
    const size_t base = (size_t)bn * S2_ * D_ + h * HD_;

    {
        const int j4   = (tid & 7) * 4;  // 4-channel chunk
        const int trow = tid >> 3;       // 0..31
        for (int it = 0; it < 8; ++it) {
            int t = it * 32 + trow;
            ushort4 kk = *(const ushort4*)(kb + base + (size_t)t * D_ + j4);
            ushort4 vv = *(const ushort4*)(vb + base + (size_t)t * D_ + j4);
            Kl[t][j4 + 0] = bf2f(kk.x); Kl[t][j4 + 1] = bf2f(kk.y);
            Kl[t][j4 + 2] = bf2f(kk.z); Kl[t][j4 + 3] = bf2f(kk.w);
            Vl[t][j4 + 0] = bf2f(vv.x); Vl[t][j4 + 1] = bf2f(vv.y);
            Vl[t][j4 + 2] = bf2f(vv.z); Vl[t][j4 + 3] = bf2f(vv.w);
        }
    }
    __syncthreads();

    const int t = tid;
    float qv[32];
    #pragma unroll
    for (int j8 = 0; j8 < 8; ++j8) {
        ushort4 qq = *(const ushort4*)(qb + base + (size_t)t * D_ + j8 * 4);
        qv[j8 * 4 + 0] = bf2f(qq.x) * 0.17677669529663687f;
        qv[j8 * 4 + 1] = bf2f(qq.y) * 0.17677669529663687f;
        qv[j8 * 4 + 2] = bf2f(qq.z) * 0.17677669529663687f;
        qv[j8 * 4 + 3] = bf2f(qq.w) * 0.17677669529663687f;
    }

    float m = -1e30f, l = 0.f;
    float acc[32];
    #pragma unroll
    for (int j = 0; j < 32; ++j) acc[j] = 0.f;

    for (int s = 0; s < 256; ++s) {
        float sc = 0.f;
        #pragma unroll
        for (int j = 0; j < 32; ++j) sc = fmaf(qv[j], Kl[s][j], sc);
        if (sc > m) {
            const float scale = __expf(m - sc);
            l *= scale;
            #pragma unroll
            for (int j = 0; j < 32; ++j) acc[j] *= scale;
            m = sc;
        }
        const float e = __expf(sc - m);
        l += e;
        #pragma unroll
        for (int j = 0; j < 32; ++j) acc[j] = fmaf(e, Vl[s][j], acc[j]);
    }

    const float inv = 1.f / l;
    #pragma unroll
    for (int j = 0; j < 32; ++j)
        ob[base + (size_t)t * D_ + j] = bf16rn(acc[j] * inv);
}

// ---------------------------------------------------------------------------
// Kernel 3: o @ Wo + bo + residual(x) -> LN(g1,be1) -> h (fp32 out), MFMA.
// o already bf16 -> LDS staging is a plain copy.
// ---------------------------------------------------------------------------
__global__ __launch_bounds__(256) void k_oproj_mfma(
    const float* __restrict__ x, const unsigned short* __restrict__ ob,
    const unsigned short* __restrict__ Wo_bt, const float* __restrict__ bo,
    const float* __restrict__ g1, const float* __restrict__ be1,
    float* __restrict__ hout)
{
    __shared__ __align__(16) unsigned short oA[32][264];
    __shared__ float yS[32][260];
    __shared__ float red[32][8][2];
    __shared__ float mu_s[32], rs_s[32];

    const int tid  = threadIdx.x;
    const int w    = tid >> 6;
    const int lane = tid & 63;
    const int col  = lane & 15;
    const int q4   = lane >> 4;
    const size_t tok0 = (size_t)blockIdx.x * 32;

    for (int i = 0; i < 32; ++i)
        oA[i][tid] = ob[(tok0 + i) * D_ + tid];
    __syncthreads();

    bfrag a[2][8];
    #pragma unroll
    for (int mt = 0; mt < 2; ++mt)
        #pragma unroll
        for (int kc = 0; kc < 8; ++kc)
            a[mt][kc] = *(const bfrag*)&oA[mt * 16 + col][kc * 32 + q4 * 8];

    f32x4 acc[4][2];
    #pragma unroll
    for (int t = 0; t < 4; ++t) {
        acc[t][0] = (f32x4){0.f, 0.f, 0.f, 0.f};
        acc[t][1] = (f32x4){0.f, 0.f, 0.f, 0.f};
    }

    for (int t = 0; t < 4; ++t) {
        const unsigned short* bp =
            Wo_bt + (size_t)((w * 4 + t) * 16 + col) * 256 + q4 * 8;
        #pragma unroll
        for (int kc = 0; kc < 8; ++kc) {
            bfrag b = *(const bfrag*)(bp + kc * 32);
            acc[t][0] = __builtin_amdgcn_mfma_f32_16x16x32_bf16(a[0][kc], b, acc[t][0], 0, 0, 0);
            acc[t][1] = __builtin_amdgcn_mfma_f32_16x16x32_bf16(a[1][kc], b, acc[t][1], 0, 0, 0);
        }
    }

    #pragma unroll
    for (int t = 0; t < 4; ++t) {
        const int n = (w * 4 + t) * 16 + col;
        #pragma unroll
        for (int mt = 0; mt < 2; ++mt)
            #pragma unroll
            for (int r = 0; r < 4; ++r)
                yS[mt * 16 + q4 * 4 + r][n] = acc[t][mt][r];
    }
    __syncthreads();

    const float bod = bo[tid];
    for (int i = 0; i < 32; ++i)
        yS[i][tid] = yS[i][tid] + bod + x[(tok0 + i) * D_ + tid];
    __syncthreads();

    {
        const int tok = tid >> 3, p = tid & 7;
        float s = 0.f, s2 = 0.f;
        for (int d = p * 32; d < p * 32 + 32; ++d) {
            const float vv = yS[tok][d];
            s += vv; s2 = fmaf(vv, vv, s2);
        }
        red[tok][p][0] = s; red[tok][p][1] = s2;
    }
    __syncthreads();
    if (tid < 32) {
        float s = 0.f, s2 = 0.f;
        #pragma unroll
        for (int p = 0; p < 8; ++p) { s += red[tid][p][0]; s2 += red[tid][p][1]; }
        const float mu  = s * (1.f / 256.f);
        const float var = s2 * (1.f / 256.f) - mu * mu;
        mu_s[tid] = mu;
        rs_s[tid] = rsqrtf(var + EPS_);
    }
    __syncthreads();

    const float g = g1[tid], be = be1[tid];
    for (int i = 0; i < 32; ++i)
        hout[(tok0 + i) * D_ + tid] = (yS[i][tid] - mu_s[i]) * rs_s[i] * g + be;
}

// ---------------------------------------------------------------------------
// Kernel 4: FFN via bf16 MFMA, fused leakyReLU + residual + LN2.
// (byte-identical to the R2-proven version)
// ---------------------------------------------------------------------------
__global__ __launch_bounds__(256) void k_ffn_mfma(
    const float* __restrict__ h,
    const unsigned short* __restrict__ W1bt, const float* __restrict__ b1,
    const unsigned short* __restrict__ W2bt, const float* __restrict__ b2,
    const float* __restrict__ g2, const float* __restrict__ be2,
    float* __restrict__ out)
{
    __shared__ __align__(16) unsigned short hA[32][264];
    __shared__ __align__(16) unsigned short ffA[32][520];
    __shared__ float red[32][8][2];
    __shared__ float mu_s[32], rs_s[32];

    const int tid  = threadIdx.x;
    const int w    = tid >> 6;
    const int lane = tid & 63;
    const int col  = lane & 15;
    const int q4   = lane >> 4;
    const size_t tok0 = (size_t)blockIdx.x * 32;

    for (int i = 0; i < 32; ++i)
        hA[i][tid] = bf16rn(h[(tok0 + i) * D_ + tid]);
    __syncthreads();

    bfrag a[2][8];
    #pragma unroll
    for (int mt = 0; mt < 2; ++mt)
        #pragma unroll
        for (int kc = 0; kc < 8; ++kc)
            a[mt][kc] = *(const bfrag*)&hA[mt * 16 + col][kc * 32 + q4 * 8];

    f32x4 acc2[2][4];
    #pragma unroll
    for (int mt = 0; mt < 2; ++mt)
        #pragma unroll
        for (int t2 = 0; t2 < 4; ++t2)
            acc2[mt][t2] = (f32x4){0.f, 0.f, 0.f, 0.f};

    for (int hf = 0; hf < 2; ++hf) {
        for (int t = 0; t < 8; ++t) {
            const int ng = hf * 512 + w * 128 + t * 16;
            const unsigned short* bp = W1bt + (size_t)(ng + col) * 256 + q4 * 8;
            f32x4 c0 = {0.f, 0.f, 0.f, 0.f}, c1 = {0.f, 0.f, 0.f, 0.f};
            #pragma unroll
            for (int kc = 0; kc < 8; ++kc) {
                bfrag b = *(const bfrag*)(bp + kc * 32);
                c0 = __builtin_amdgcn_mfma_f32_16x16x32_bf16(a[0][kc], b, c0, 0, 0, 0);
                c1 = __builtin_amdgcn_mfma_f32_16x16x32_bf16(a[1][kc], b, c1, 0, 0, 0);
            }
            const float bb   = b1[ng + col];
            const int   nloc = w * 128 + t * 16 + col;
            #pragma unroll
            for (int r = 0; r < 4; ++r) {
                float v0 = c0[r] + bb; v0 = (v0 > 0.f) ? v0 : NEG_ * v0;
                float v1 = c1[r] + bb; v1 = (v1 > 0.f) ? v1 : NEG_ * v1;
                ffA[q4 * 4 + r][nloc]      = bf16rn(v0);
                ffA[16 + q4 * 4 + r][nloc] = bf16rn(v1);
            }
        }
        __syncthreads();

        for (int kc = 0; kc < 16; ++kc) {
            bfrag a0 = *(const bfrag*)&ffA[col][kc * 32 + q4 * 8];
            bfrag a1 = *(const bfrag*)&ffA[16 + col][kc * 32 + q4 * 8];
            #pragma unroll
            for (int t2 = 0; t2 < 4; ++t2) {
                const int d0 = w * 64 + t2 * 16;
                bfrag b = *(const bfrag*)(W2bt + (size_t)(d0 + col) * F_
                                          + hf * 512 + kc * 32 + q4 * 8);
                acc2[0][t2] = __builtin_amdgcn_mfma_f32_16x16x32_bf16(a0, b, acc2[0][t2], 0, 0, 0);
                acc2[1][t2] = __builtin_amdgcn_mfma_f32_16x16x32_bf16(a1, b, acc2[1][t2], 0, 0, 0);
            }
        }
        __syncthreads();
    }

    float* yS = (float*)&ffA[0][0];
    #pragma unroll
    for (int mt = 0; mt < 2; ++mt)
        #pragma unroll
        for (int t2 = 0; t2 < 4; ++t2)
            #pragma unroll
            for (int r = 0; r < 4; ++r)
                yS[(mt * 16 + q4 * 4 + r) * 260 + (w * 64 + t2 * 16 + col)] = acc2[mt][t2][r];
    __syncthreads();

    const float b2d = b2[tid];
    for (int i = 0; i < 32; ++i) {
        float val = yS[i * 260 + tid] + b2d + h[(tok0 + i) * D_ + tid];
        yS[i * 260 + tid] = val;
    }
    __syncthreads();

    {
        const int tok = tid >> 3, p = tid & 7;
        float s = 0.f, s2 = 0.f;
        for (int d = p * 32; d < p * 32 + 32; ++d) {
            const float vv = yS[tok * 260 + d];
            s += vv; s2 = fmaf(vv, vv, s2);
        }
        red[tok][p][0] = s; red[tok][p][1] = s2;
    }
    __syncthreads();
    if (tid < 32) {
        float s = 0.f, s2 = 0.f;
        #pragma unroll
        for (int p = 0; p < 8; ++p) { s += red[tid][p][0]; s2 += red[tid][p][1]; }
        const float mu  = s * (1.f / 256.f);
        const float var = s2 * (1.f / 256.f) - mu * mu;
        mu_s[tid] = mu;
        rs_s[tid] = rsqrtf(var + EPS_);
    }
    __syncthreads();

    const float g = g2[tid], be = be2[tid];
    for (int i = 0; i < 32; ++i)
        out[(tok0 + i) * D_ + tid] = (yS[i * 260 + tid] - mu_s[i]) * rs_s[i] * g + be;
}

// ---------------------------------------------------------------------------
extern "C" void kernel_launch(void* const* d_in, const int* in_sizes, int n_in,
                              void* d_out, int out_size, void* d_ws, size_t ws_size,
                              hipStream_t stream)
{
    const float* x   = (const float*)d_in[0];
    const float* Wq  = (const float*)d_in[1];
    const float* bq  = (const float*)d_in[2];
    const float* Wk  = (const float*)d_in[3];
    const float* bk  = (const float*)d_in[4];
    const float* Wv  = (const float*)d_in[5];
    const float* bv  = (const float*)d_in[6];
    const float* Wo  = (const float*)d_in[7];
    const float* bo  = (const float*)d_in[8];
    const float* W1  = (const float*)d_in[9];
    const float* b1  = (const float*)d_in[10];
    const float* W2  = (const float*)d_in[11];
    const float* b2  = (const float*)d_in[12];
    const float* g1  = (const float*)d_in[13];
    const float* be1 = (const float*)d_in[14];
    const float* g2  = (const float*)d_in[15];
    const float* be2 = (const float*)d_in[16];
    float* out = (float*)d_out;

    const size_t N = (size_t)B_ * S1_ * S2_ * D_;   // 16,777,216 elements

    // Dedicated, NON-ALIASED workspace layout:
    //   qb/kb/vb/ob : bf16 activations, N shorts each      (4 x 32 MB)
    //   h           : fp32,  N floats                      (64 MB)
    //   weights     : bf16 transposed copies               (~2 MB)
    unsigned short* qb  = (unsigned short*)d_ws;
    unsigned short* kb  = qb + N;
    unsigned short* vb  = kb + N;
    unsigned short* ob  = vb + N;
    float*          h   = (float*)(ob + N);
    unsigned short* Wqk_bt = (unsigned short*)(h + N);
    unsigned short* Wv_bt  = Wqk_bt + (size_t)512 * 768;
    unsigned short* Wo_bt  = Wv_bt  + (size_t)256 * 256;
    unsigned short* W1bt   = Wo_bt  + (size_t)256 * 256;
    unsigned short* W2bt   = W1bt   + (size_t)F_ * D_;
    const size_t need = (size_t)(W2bt + (size_t)D_ * F_ - (unsigned short*)d_ws) * 2;
    if (ws_size < need) return;

    k_cvt_qkv   <<<dim3(768),  256, 0, stream>>>(Wq, Wk, Wv, Wqk_bt, Wv_bt);
    k_cvt_proj  <<<dim3(1536), 256, 0, stream>>>(Wo, W1, W2, Wo_bt, W1bt, W2bt);
    k_qkv_mfma  <<<dim3(B_ * S1_ * S2_ / 32), 256, 0, stream>>>(
                    x, Wqk_bt, Wv_bt, bq, bk, bv, qb, kb, vb);
    k_attn      <<<dim3(B_ * S1_, H_), 256, 0, stream>>>(qb, kb, vb, ob);
    k_oproj_mfma<<<dim3(B_ * S1_ * S2_ / 32), 256, 0, stream>>>(
                    x, ob, Wo_bt, bo, g1, be1, h);
    k_ffn_mfma  <<<dim3(B_ * S1_ * S2_ / 32), 256, 0, stream>>>(
                    h, W1bt, b1, W2bt, b2, g2, be2, out);
}

// Round 5
// 990.684 us; speedup vs baseline: 2.6712x; 1.1326x over previous
//
#include <hip/hip_runtime.h>
#include <hip/hip_bf16.h>

// Problem constants
#define B_ 4
#define S1_ 64
#define S2_ 256
#define D_ 256
#define H_ 8
#define HD_ 32
#define F_ 1024
#define EPS_ 1e-5f
#define NEG_ 0.01f

typedef __attribute__((ext_vector_type(8))) short bfrag;   // 8 x bf16 (4 VGPRs)
typedef __attribute__((ext_vector_type(4))) float f32x4;   // MFMA C/D
typedef __attribute__((ext_vector_type(8))) unsigned short us8;

__device__ __forceinline__ unsigned short bf16rn(float f) {
    union { float f; unsigned int u; } c; c.f = f;
    unsigned int u = c.u;
    u = (u + 0x7FFFu + ((u >> 16) & 1u)) >> 16;   // round-to-nearest-even
    return (unsigned short)u;
}
__device__ __forceinline__ float bf2f(unsigned short s) {
    union { unsigned int u; float f; } c; c.u = ((unsigned int)s) << 16;
    return c.f;
}

// ---------------------------------------------------------------------------
// Weight transpose+cast: Wq/Wk [s][i][c] -> Wqk_bt [n=512][k=768] (n<256: q)
//                        Wv [i][c]      -> Wv_bt  [n=256][k=256]
// ---------------------------------------------------------------------------
__global__ __launch_bounds__(256) void k_cvt_qkv(
    const float* __restrict__ Wq, const float* __restrict__ Wk,
    const float* __restrict__ Wv,
    unsigned short* __restrict__ Wqk_bt, unsigned short* __restrict__ Wv_bt)
{
    const int blk = blockIdx.x;      // 0..767
    const int i   = threadIdx.x;     // 0..255 (in-channel)
    if (blk < 256) {
        const int n = blk;
        #pragma unroll
        for (int s = 0; s < 3; ++s)
            Wqk_bt[(size_t)n * 768 + s * 256 + i] = bf16rn(Wq[((size_t)s * 256 + i) * 256 + n]);
    } else if (blk < 512) {
        const int n = blk; const int c = blk - 256;
        #pragma unroll
        for (int s = 0; s < 3; ++s)
            Wqk_bt[(size_t)n * 768 + s * 256 + i] = bf16rn(Wk[((size_t)s * 256 + i) * 256 + c]);
    } else {
        const int c = blk - 512;
        Wv_bt[(size_t)c * 256 + i] = bf16rn(Wv[(size_t)i * 256 + c]);
    }
}

// Wo [k][n] -> Wo_bt [n=256][k=256]; W1 [k][n] -> W1bt [n=1024][k=256];
// W2 [f][d] -> W2bt [d=256][f=1024]
__global__ __launch_bounds__(256) void k_cvt_proj(
    const float* __restrict__ Wo, const float* __restrict__ W1,
    const float* __restrict__ W2,
    unsigned short* __restrict__ Wo_bt, unsigned short* __restrict__ W1bt,
    unsigned short* __restrict__ W2bt)
{
    const int blk = blockIdx.x;      // 0..1535
    const int t   = threadIdx.x;
    if (blk < 256) {
        Wo_bt[(size_t)blk * 256 + t] = bf16rn(Wo[(size_t)t * 256 + blk]);
    } else if (blk < 1280) {
        const int n = blk - 256;     // 0..1023
        W1bt[(size_t)n * 256 + t] = bf16rn(W1[(size_t)t * F_ + n]);
    } else {
        const int d = blk - 1280;    // 0..255
        for (int f = t; f < F_; f += 256)
            W2bt[(size_t)d * F_ + f] = bf16rn(W2[(size_t)f * D_ + d]);
    }
}

// ---------------------------------------------------------------------------
// Kernel 1: q/k time-conv + v projection as bf16 MFMA GEMM. (unchanged)
// ---------------------------------------------------------------------------
__global__ __launch_bounds__(256) void k_qkv_mfma(
    const float* __restrict__ x,
    const unsigned short* __restrict__ Wqk_bt,
    const unsigned short* __restrict__ Wv_bt,
    const float* __restrict__ bq, const float* __restrict__ bk,
    const float* __restrict__ bv,
    unsigned short* __restrict__ qb, unsigned short* __restrict__ kb,
    unsigned short* __restrict__ vb)
{
    __shared__ __align__(16) unsigned short xA[34][264];
    const int tid  = threadIdx.x;
    const int w    = tid >> 6;
    const int lane = tid & 63;
    const int col  = lane & 15;
    const int q4   = lane >> 4;
    const int bn   = blockIdx.x >> 3;           // (b*S1+n)
    const int t0   = (blockIdx.x & 7) * 32;
    const float* xb = x + (size_t)bn * S2_ * D_;

    for (int r = 0; r < 34; ++r) {
        const int t = t0 - 1 + r;
        xA[r][tid] = (t >= 0 && t < S2_) ? bf16rn(xb[(size_t)t * D_ + tid])
                                         : (unsigned short)0;
    }
    __syncthreads();

    // ---- q/k: K = 768, shift-major ----
    f32x4 accqk[8][2];
    #pragma unroll
    for (int t = 0; t < 8; ++t)
        #pragma unroll
        for (int mt = 0; mt < 2; ++mt)
            accqk[t][mt] = (f32x4){0.f, 0.f, 0.f, 0.f};

    for (int s = 0; s < 3; ++s) {
        bfrag a[2][8];
        #pragma unroll
        for (int mt = 0; mt < 2; ++mt)
            #pragma unroll
            for (int kc = 0; kc < 8; ++kc)
                a[mt][kc] = *(const bfrag*)&xA[mt * 16 + col + s][kc * 32 + q4 * 8];

        for (int t = 0; t < 8; ++t) {
            const unsigned short* bp =
                Wqk_bt + (size_t)((w * 8 + t) * 16 + col) * 768 + s * 256 + q4 * 8;
            #pragma unroll
            for (int kc = 0; kc < 8; ++kc) {
                bfrag b = *(const bfrag*)(bp + kc * 32);
                accqk[t][0] = __builtin_amdgcn_mfma_f32_16x16x32_bf16(a[0][kc], b, accqk[t][0], 0, 0, 0);
                accqk[t][1] = __builtin_amdgcn_mfma_f32_16x16x32_bf16(a[1][kc], b, accqk[t][1], 0, 0, 0);
            }
        }
    }

    #pragma unroll
    for (int t = 0; t < 8; ++t) {
        const int n = (w * 8 + t) * 16 + col;   // 0..511
        const float bias = (n < 256) ? bq[n] : bk[n - 256];
        unsigned short* dst = (n < 256) ? qb : kb;
        const int c = n & 255;
        #pragma unroll
        for (int mt = 0; mt < 2; ++mt)
            #pragma unroll
            for (int r = 0; r < 4; ++r)
                dst[((size_t)bn * S2_ + t0 + mt * 16 + q4 * 4 + r) * D_ + c]
                    = bf16rn(accqk[t][mt][r] + bias);
    }

    // ---- v: K = 256, center shift ----
    f32x4 accv[4][2];
    #pragma unroll
    for (int t = 0; t < 4; ++t) {
        accv[t][0] = (f32x4){0.f, 0.f, 0.f, 0.f};
        accv[t][1] = (f32x4){0.f, 0.f, 0.f, 0.f};
    }
    bfrag a1[2][8];
    #pragma unroll
    for (int mt = 0; mt < 2; ++mt)
        #pragma unroll
        for (int kc = 0; kc < 8; ++kc)
            a1[mt][kc] = *(const bfrag*)&xA[mt * 16 + col + 1][kc * 32 + q4 * 8];

    for (int t = 0; t < 4; ++t) {
        const unsigned short* bp =
            Wv_bt + (size_t)((w * 4 + t) * 16 + col) * 256 + q4 * 8;
        #pragma unroll
        for (int kc = 0; kc < 8; ++kc) {
            bfrag b = *(const bfrag*)(bp + kc * 32);
            accv[t][0] = __builtin_amdgcn_mfma_f32_16x16x32_bf16(a1[0][kc], b, accv[t][0], 0, 0, 0);
            accv[t][1] = __builtin_amdgcn_mfma_f32_16x16x32_bf16(a1[1][kc], b, accv[t][1], 0, 0, 0);
        }
    }

    #pragma unroll
    for (int t = 0; t < 4; ++t) {
        const int c = (w * 4 + t) * 16 + col;
        const float bias = bv[c];
        #pragma unroll
        for (int mt = 0; mt < 2; ++mt)
            #pragma unroll
            for (int r = 0; r < 4; ++r)
                vb[((size_t)bn * S2_ + t0 + mt * 16 + q4 * 4 + r) * D_ + c]
                    = bf16rn(accv[t][mt][r] + bias);
    }
}

// ---------------------------------------------------------------------------
// Kernel 2: MFMA attention. One block per (bn, head); 4 waves; each wave
// independently owns 64 query rows (4 m-tiles of 16). S2=256 keys fit in
// LDS, so softmax is single-pass (no online rescale). HD=32 = one K=32 MFMA.
//   QK^T:  A = Q rows (frags direct from global), B^T = K rows (LDS).
//   P:     C-layout -> bf16 -> per-wave LDS scratch (A-layout), no barriers.
//   PV:    A = P, B^T = V^T (LDS, transposed at stage).
// ---------------------------------------------------------------------------
__global__ __launch_bounds__(256) void k_attn_mfma(
    const unsigned short* __restrict__ qb, const unsigned short* __restrict__ kb,
    const unsigned short* __restrict__ vb, unsigned short* __restrict__ ob)
{
    __shared__ __align__(16) unsigned short Ks[256][40];   // keys, pad->bank spread
    __shared__ __align__(16) unsigned short Vt[32][264];   // V transposed [d][s]
    __shared__ __align__(16) unsigned short Pw[4][16][264];// per-wave P scratch

    const int bn   = blockIdx.x;
    const int h    = blockIdx.y;
    const int tid  = threadIdx.x;
    const int w    = tid >> 6;
    const int lane = tid & 63;
    const int col  = lane & 15;
    const int q4   = lane >> 4;
    const size_t base = (size_t)bn * S2_ * D_ + h * HD_;
    const float SCALE = 0.17677669529663687f;   // 1/sqrt(32)

    // ---- stage K rows (coalesced 64B/row) ----
    {
        const unsigned short* kr = kb + base + (size_t)tid * D_;
        #pragma unroll
        for (int j = 0; j < 4; ++j)
            *(us8*)&Ks[tid][j * 8] = *(const us8*)(kr + j * 8);
    }
    // ---- stage V transposed: thread (dv, sg) covers d=dv, s=sg*32..+31 ----
    {
        const int dv = tid & 31, sg = tid >> 5;
        for (int i = 0; i < 32; ++i) {
            const int s = sg * 32 + i;
            Vt[dv][s] = vb[base + (size_t)s * D_ + dv];
        }
    }
    __syncthreads();

    // ---- Q fragments direct from global (A-layout) ----
    const int r0w = w * 64;
    bfrag qa[4];
    #pragma unroll
    for (int mt = 0; mt < 4; ++mt)
        qa[mt] = *(const bfrag*)(qb + base + (size_t)(r0w + mt * 16 + col) * D_ + q4 * 8);

    for (int mt = 0; mt < 4; ++mt) {
        // ---- scores: 16 n-tiles, one MFMA each (K=32 = full HD) ----
        f32x4 sc[16];
        #pragma unroll
        for (int nt = 0; nt < 16; ++nt) {
            bfrag b = *(const bfrag*)&Ks[nt * 16 + col][q4 * 8];
            f32x4 z = {0.f, 0.f, 0.f, 0.f};
            sc[nt] = __builtin_amdgcn_mfma_f32_16x16x32_bf16(qa[mt], b, z, 0, 0, 0);
        }

        // ---- softmax over 256 cols; row r_global = r0w+mt*16+q4*4+r ----
        float mx[4] = {-1e30f, -1e30f, -1e30f, -1e30f};
        #pragma unroll
        for (int nt = 0; nt < 16; ++nt)
            #pragma unroll
            for (int r = 0; r < 4; ++r) {
                sc[nt][r] *= SCALE;
                mx[r] = fmaxf(mx[r], sc[nt][r]);
            }
        #pragma unroll
        for (int r = 0; r < 4; ++r) {
            mx[r] = fmaxf(mx[r], __shfl_xor(mx[r], 1));
            mx[r] = fmaxf(mx[r], __shfl_xor(mx[r], 2));
            mx[r] = fmaxf(mx[r], __shfl_xor(mx[r], 4));
            mx[r] = fmaxf(mx[r], __shfl_xor(mx[r], 8));
        }
        float l[4] = {0.f, 0.f, 0.f, 0.f};
        #pragma unroll
        for (int nt = 0; nt < 16; ++nt)
            #pragma unroll
            for (int r = 0; r < 4; ++r) {
                const float e = __expf(sc[nt][r] - mx[r]);
                sc[nt][r] = e;
                l[r] += e;
            }
        #pragma unroll
        for (int r = 0; r < 4; ++r) {
            l[r] += __shfl_xor(l[r], 1);
            l[r] += __shfl_xor(l[r], 2);
            l[r] += __shfl_xor(l[r], 4);
            l[r] += __shfl_xor(l[r], 8);
        }

        // ---- P -> per-wave LDS (bf16), even-lane packed u32 writes ----
        #pragma unroll
        for (int nt = 0; nt < 16; ++nt)
            #pragma unroll
            for (int r = 0; r < 4; ++r) {
                const float p  = sc[nt][r];
                const float po = __shfl_xor(p, 1);
                if ((lane & 1) == 0) {
                    const unsigned int packed =
                        (unsigned int)bf16rn(p) | ((unsigned int)bf16rn(po) << 16);
                    *(unsigned int*)&Pw[w][q4 * 4 + r][nt * 16 + col] = packed;
                }
            }
        // same-wave DS ordering: reads below see the writes (in-order DS pipe)

        // ---- PV: o[16 x 32] ----
        f32x4 oacc[2];
        oacc[0] = (f32x4){0.f, 0.f, 0.f, 0.f};
        oacc[1] = (f32x4){0.f, 0.f, 0.f, 0.f};
        #pragma unroll
        for (int kc = 0; kc < 8; ++kc) {
            bfrag pa = *(const bfrag*)&Pw[w][col][kc * 32 + q4 * 8];
            #pragma unroll
            for (int dt = 0; dt < 2; ++dt) {
                bfrag b = *(const bfrag*)&Vt[dt * 16 + col][kc * 32 + q4 * 8];
                oacc[dt] = __builtin_amdgcn_mfma_f32_16x16x32_bf16(pa, b, oacc[dt], 0, 0, 0);
            }
        }

        // ---- normalize + write ----
        float inv[4];
        #pragma unroll
        for (int r = 0; r < 4; ++r) inv[r] = 1.f / l[r];
        #pragma unroll
        for (int dt = 0; dt < 2; ++dt)
            #pragma unroll
            for (int r = 0; r < 4; ++r)
                ob[base + (size_t)(r0w + mt * 16 + q4 * 4 + r) * D_ + dt * 16 + col]
                    = bf16rn(oacc[dt][r] * inv[r]);
    }
}

// ---------------------------------------------------------------------------
// Kernel 3: o @ Wo + bo + residual(x) -> LN(g1,be1) -> h (fp32 out), MFMA.
// (unchanged)
// ---------------------------------------------------------------------------
__global__ __launch_bounds__(256) void k_oproj_mfma(
    const float* __restrict__ x, const unsigned short* __restrict__ ob,
    const unsigned short* __restrict__ Wo_bt, const float* __restrict__ bo,
    const float* __restrict__ g1, const float* __restrict__ be1,
    float* __restrict__ hout)
{
    __shared__ __align__(16) unsigned short oA[32][264];
    __shared__ float yS[32][260];
    __shared__ float red[32][8][2];
    __shared__ float mu_s[32], rs_s[32];

    const int tid  = threadIdx.x;
    const int w    = tid >> 6;
    const int lane = tid & 63;
    const int col  = lane & 15;
    const int q4   = lane >> 4;
    const size_t tok0 = (size_t)blockIdx.x * 32;

    for (int i = 0; i < 32; ++i)
        oA[i][tid] = ob[(tok0 + i) * D_ + tid];
    __syncthreads();

    bfrag a[2][8];
    #pragma unroll
    for (int mt = 0; mt < 2; ++mt)
        #pragma unroll
        for (int kc = 0; kc < 8; ++kc)
            a[mt][kc] = *(const bfrag*)&oA[mt * 16 + col][kc * 32 + q4 * 8];

    f32x4 acc[4][2];
    #pragma unroll
    for (int t = 0; t < 4; ++t) {
        acc[t][0] = (f32x4){0.f, 0.f, 0.f, 0.f};
        acc[t][1] = (f32x4){0.f, 0.f, 0.f, 0.f};
    }

    for (int t = 0; t < 4; ++t) {
        const unsigned short* bp =
            Wo_bt + (size_t)((w * 4 + t) * 16 + col) * 256 + q4 * 8;
        #pragma unroll
        for (int kc = 0; kc < 8; ++kc) {
            bfrag b = *(const bfrag*)(bp + kc * 32);
            acc[t][0] = __builtin_amdgcn_mfma_f32_16x16x32_bf16(a[0][kc], b, acc[t][0], 0, 0, 0);
            acc[t][1] = __builtin_amdgcn_mfma_f32_16x16x32_bf16(a[1][kc], b, acc[t][1], 0, 0, 0);
        }
    }

    #pragma unroll
    for (int t = 0; t < 4; ++t) {
        const int n = (w * 4 + t) * 16 + col;
        #pragma unroll
        for (int mt = 0; mt < 2; ++mt)
            #pragma unroll
            for (int r = 0; r < 4; ++r)
                yS[mt * 16 + q4 * 4 + r][n] = acc[t][mt][r];
    }
    __syncthreads();

    const float bod = bo[tid];
    for (int i = 0; i < 32; ++i)
        yS[i][tid] = yS[i][tid] + bod + x[(tok0 + i) * D_ + tid];
    __syncthreads();

    {
        const int tok = tid >> 3, p = tid & 7;
        float s = 0.f, s2 = 0.f;
        for (int d = p * 32; d < p * 32 + 32; ++d) {
            const float vv = yS[tok][d];
            s += vv; s2 = fmaf(vv, vv, s2);
        }
        red[tok][p][0] = s; red[tok][p][1] = s2;
    }
    __syncthreads();
    if (tid < 32) {
        float s = 0.f, s2 = 0.f;
        #pragma unroll
        for (int p = 0; p < 8; ++p) { s += red[tid][p][0]; s2 += red[tid][p][1]; }
        const float mu  = s * (1.f / 256.f);
        const float var = s2 * (1.f / 256.f) - mu * mu;
        mu_s[tid] = mu;
        rs_s[tid] = rsqrtf(var + EPS_);
    }
    __syncthreads();

    const float g = g1[tid], be = be1[tid];
    for (int i = 0; i < 32; ++i)
        hout[(tok0 + i) * D_ + tid] = (yS[i][tid] - mu_s[i]) * rs_s[i] * g + be;
}

// ---------------------------------------------------------------------------
// Kernel 4: FFN via bf16 MFMA, fused leakyReLU + residual + LN2. (unchanged)
// ---------------------------------------------------------------------------
__global__ __launch_bounds__(256) void k_ffn_mfma(
    const float* __restrict__ h,
    const unsigned short* __restrict__ W1bt, const float* __restrict__ b1,
    const unsigned short* __restrict__ W2bt, const float* __restrict__ b2,
    const float* __restrict__ g2, const float* __restrict__ be2,
    float* __restrict__ out)
{
    __shared__ __align__(16) unsigned short hA[32][264];
    __shared__ __align__(16) unsigned short ffA[32][520];
    __shared__ float red[32][8][2];
    __shared__ float mu_s[32], rs_s[32];

    const int tid  = threadIdx.x;
    const int w    = tid >> 6;
    const int lane = tid & 63;
    const int col  = lane & 15;
    const int q4   = lane >> 4;
    const size_t tok0 = (size_t)blockIdx.x * 32;

    for (int i = 0; i < 32; ++i)
        hA[i][tid] = bf16rn(h[(tok0 + i) * D_ + tid]);
    __syncthreads();

    bfrag a[2][8];
    #pragma unroll
    for (int mt = 0; mt < 2; ++mt)
        #pragma unroll
        for (int kc = 0; kc < 8; ++kc)
            a[mt][kc] = *(const bfrag*)&hA[mt * 16 + col][kc * 32 + q4 * 8];

    f32x4 acc2[2][4];
    #pragma unroll
    for (int mt = 0; mt < 2; ++mt)
        #pragma unroll
        for (int t2 = 0; t2 < 4; ++t2)
            acc2[mt][t2] = (f32x4){0.f, 0.f, 0.f, 0.f};

    for (int hf = 0; hf < 2; ++hf) {
        for (int t = 0; t < 8; ++t) {
            const int ng = hf * 512 + w * 128 + t * 16;
            const unsigned short* bp = W1bt + (size_t)(ng + col) * 256 + q4 * 8;
            f32x4 c0 = {0.f, 0.f, 0.f, 0.f}, c1 = {0.f, 0.f, 0.f, 0.f};
            #pragma unroll
            for (int kc = 0; kc < 8; ++kc) {
                bfrag b = *(const bfrag*)(bp + kc * 32);
                c0 = __builtin_amdgcn_mfma_f32_16x16x32_bf16(a[0][kc], b, c0, 0, 0, 0);
                c1 = __builtin_amdgcn_mfma_f32_16x16x32_bf16(a[1][kc], b, c1, 0, 0, 0);
            }
            const float bb   = b1[ng + col];
            const int   nloc = w * 128 + t * 16 + col;
            #pragma unroll
            for (int r = 0; r < 4; ++r) {
                float v0 = c0[r] + bb; v0 = (v0 > 0.f) ? v0 : NEG_ * v0;
                float v1 = c1[r] + bb; v1 = (v1 > 0.f) ? v1 : NEG_ * v1;
                ffA[q4 * 4 + r][nloc]      = bf16rn(v0);
                ffA[16 + q4 * 4 + r][nloc] = bf16rn(v1);
            }
        }
        __syncthreads();

        for (int kc = 0; kc < 16; ++kc) {
            bfrag a0 = *(const bfrag*)&ffA[col][kc * 32 + q4 * 8];
            bfrag a1 = *(const bfrag*)&ffA[16 + col][kc * 32 + q4 * 8];
            #pragma unroll
            for (int t2 = 0; t2 < 4; ++t2) {
                const int d0 = w * 64 + t2 * 16;
                bfrag b = *(const bfrag*)(W2bt + (size_t)(d0 + col) * F_
                                          + hf * 512 + kc * 32 + q4 * 8);
                acc2[0][t2] = __builtin_amdgcn_mfma_f32_16x16x32_bf16(a0, b, acc2[0][t2], 0, 0, 0);
                acc2[1][t2] = __builtin_amdgcn_mfma_f32_16x16x32_bf16(a1, b, acc2[1][t2], 0, 0, 0);
            }
        }
        __syncthreads();
    }

    float* yS = (float*)&ffA[0][0];
    #pragma unroll
    for (int mt = 0; mt < 2; ++mt)
        #pragma unroll
        for (int t2 = 0; t2 < 4; ++t2)
            #pragma unroll
            for (int r = 0; r < 4; ++r)
                yS[(mt * 16 + q4 * 4 + r) * 260 + (w * 64 + t2 * 16 + col)] = acc2[mt][t2][r];
    __syncthreads();

    const float b2d = b2[tid];
    for (int i = 0; i < 32; ++i) {
        float val = yS[i * 260 + tid] + b2d + h[(tok0 + i) * D_ + tid];
        yS[i * 260 + tid] = val;
    }
    __syncthreads();

    {
        const int tok = tid >> 3, p = tid & 7;
        float s = 0.f, s2 = 0.f;
        for (int d = p * 32; d < p * 32 + 32; ++d) {
            const float vv = yS[tok * 260 + d];
            s += vv; s2 = fmaf(vv, vv, s2);
        }
        red[tok][p][0] = s; red[tok][p][1] = s2;
    }
    __syncthreads();
    if (tid < 32) {
        float s = 0.f, s2 = 0.f;
        #pragma unroll
        for (int p = 0; p < 8; ++p) { s += red[tid][p][0]; s2 += red[tid][p][1]; }
        const float mu  = s * (1.f / 256.f);
        const float var = s2 * (1.f / 256.f) - mu * mu;
        mu_s[tid] = mu;
        rs_s[tid] = rsqrtf(var + EPS_);
    }
    __syncthreads();

    const float g = g2[tid], be = be2[tid];
    for (int i = 0; i < 32; ++i)
        out[(tok0 + i) * D_ + tid] = (yS[i * 260 + tid] - mu_s[i]) * rs_s[i] * g + be;
}

// ---------------------------------------------------------------------------
extern "C" void kernel_launch(void* const* d_in, const int* in_sizes, int n_in,
                              void* d_out, int out_size, void* d_ws, size_t ws_size,
                              hipStream_t stream)
{
    const float* x   = (const float*)d_in[0];
    const float* Wq  = (const float*)d_in[1];
    const float* bq  = (const float*)d_in[2];
    const float* Wk  = (const float*)d_in[3];
    const float* bk  = (const float*)d_in[4];
    const float* Wv  = (const float*)d_in[5];
    const float* bv  = (const float*)d_in[6];
    const float* Wo  = (const float*)d_in[7];
    const float* bo  = (const float*)d_in[8];
    const float* W1  = (const float*)d_in[9];
    const float* b1  = (const float*)d_in[10];
    const float* W2  = (const float*)d_in[11];
    const float* b2  = (const float*)d_in[12];
    const float* g1  = (const float*)d_in[13];
    const float* be1 = (const float*)d_in[14];
    const float* g2  = (const float*)d_in[15];
    const float* be2 = (const float*)d_in[16];
    float* out = (float*)d_out;

    const size_t N = (size_t)B_ * S1_ * S2_ * D_;   // 16,777,216 elements

    // Dedicated, NON-ALIASED workspace layout:
    unsigned short* qb  = (unsigned short*)d_ws;
    unsigned short* kb  = qb + N;
    unsigned short* vb  = kb + N;
    unsigned short* ob  = vb + N;
    float*          h   = (float*)(ob + N);
    unsigned short* Wqk_bt = (unsigned short*)(h + N);
    unsigned short* Wv_bt  = Wqk_bt + (size_t)512 * 768;
    unsigned short* Wo_bt  = Wv_bt  + (size_t)256 * 256;
    unsigned short* W1bt   = Wo_bt  + (size_t)256 * 256;
    unsigned short* W2bt   = W1bt   + (size_t)F_ * D_;
    const size_t need = (size_t)(W2bt + (size_t)D_ * F_ - (unsigned short*)d_ws) * 2;
    if (ws_size < need) return;

    k_cvt_qkv   <<<dim3(768),  256, 0, stream>>>(Wq, Wk, Wv, Wqk_bt, Wv_bt);
    k_cvt_proj  <<<dim3(1536), 256, 0, stream>>>(Wo, W1, W2, Wo_bt, W1bt, W2bt);
    k_qkv_mfma  <<<dim3(B_ * S1_ * S2_ / 32), 256, 0, stream>>>(
                    x, Wqk_bt, Wv_bt, bq, bk, bv, qb, kb, vb);
    k_attn_mfma <<<dim3(B_ * S1_, H_), 256, 0, stream>>>(qb, kb, vb, ob);
    k_oproj_mfma<<<dim3(B_ * S1_ * S2_ / 32), 256, 0, stream>>>(
                    x, ob, Wo_bt, bo, g1, be1, h);
    k_ffn_mfma  <<<dim3(B_ * S1_ * S2_ / 32), 256, 0, stream>>>(
                    h, W1bt, b1, W2bt, b2, g2, be2, out);
}